// Round 1
// baseline (341.749 us; speedup 1.0000x reference)
//
#include <hip/hip_runtime.h>

// ---------- types ----------
typedef __attribute__((ext_vector_type(8))) short s8vec;
typedef __attribute__((ext_vector_type(8))) __bf16 bf8vec;
typedef __attribute__((ext_vector_type(4))) float f4vec;

__device__ __forceinline__ unsigned short f2bf(float f) {
  unsigned u = __float_as_uint(f);
  u += 0x7fffu + ((u >> 16) & 1u);          // RNE, finite values only
  return (unsigned short)(u >> 16);
}

__device__ __forceinline__ f4vec MFMA(s8vec a, s8vec b, f4vec c) {
  return __builtin_amdgcn_mfma_f32_16x16x32_bf16(
      __builtin_bit_cast(bf8vec, a), __builtin_bit_cast(bf8vec, b), c, 0, 0, 0);
}

// ---------- constants ----------
// B=32, H=W=64, C=128, S=8, NH=4, HD=32. Tokens M = 131072. Windows = 2048.

// ---------- K0: weight fp32 -> bf16 ----------
__global__ __launch_bounds__(256) void wconv_k(
    const float* __restrict__ qkvw, const float* __restrict__ projw,
    const float* __restrict__ f1w, const float* __restrict__ f2w,
    short* __restrict__ out) {
  int i = blockIdx.x * 256 + threadIdx.x;     // grid covers 196608 exactly
  float v;
  if (i < 49152)        v = qkvw[i];
  else if (i < 65536)   v = projw[i - 49152];
  else if (i < 131072)  v = f1w[i - 65536];
  else                  v = f2w[i - 131072];
  out[i] = (short)f2bf(v);
}

// ---------- K1/K5: LayerNorm (PERM=1: roll+window permute gather) ----------
template <int PERM>
__global__ __launch_bounds__(256) void ln_k(
    const float* __restrict__ in, const float* __restrict__ w,
    const float* __restrict__ bv, short* __restrict__ out) {
  int t = blockIdx.x * 4 + (threadIdx.x >> 6);   // token (window order if PERM)
  int lane = threadIdx.x & 63;
  size_t src;
  if (PERM) {
    int wi = t >> 6, n = t & 63;
    int bb = wi >> 6, hy = (wi >> 3) & 7, wx = wi & 7;
    int sy = n >> 3, sx = n & 7;
    int py = (sy * 8 + hy + 8) & 63, px = (sx * 8 + wx + 8) & 63;
    src = ((size_t)(bb * 4096 + py * 64 + px)) * 128;
  } else {
    src = (size_t)t * 128;
  }
  float2 v = *(const float2*)(in + src + lane * 2);
  float s = v.x + v.y, sq = v.x * v.x + v.y * v.y;
#pragma unroll
  for (int m = 1; m < 64; m <<= 1) {
    s += __shfl_xor(s, m);
    sq += __shfl_xor(sq, m);
  }
  float mean = s * 0.0078125f;
  float var = sq * 0.0078125f - mean * mean;
  float rs = rsqrtf(var + 1e-5f);
  float w0 = w[lane * 2], w1 = w[lane * 2 + 1];
  float b0 = bv[lane * 2], b1 = bv[lane * 2 + 1];
  unsigned p = (unsigned)f2bf((v.x - mean) * rs * w0 + b0) |
               ((unsigned)f2bf((v.y - mean) * rs * w1 + b1) << 16);
  *(unsigned*)(out + (size_t)t * 128 + lane * 2) = p;
}

// ---------- GEMM: C[M,N] = A[M,K] * W[N,K]^T, bf16 in, epilogue per MODE ----------
// MODE 0: +qkv_b, scatter to (win,head,{q,k,vT}) layout, bf16
// MODE 1: +proj_b, un-permute + residual(x) -> msa fp32 (outf)
// MODE 2: +fc1_b, exact GELU -> bf16 (outb)
// MODE 3: +fc2_b + res (== outf, in-place) -> fp32
template <int MODE, int KTOT>
__global__ __launch_bounds__(256) void gemm_k(
    const short* __restrict__ A, const short* __restrict__ W,
    const float* __restrict__ bias, short* __restrict__ outb,
    float* outf, const float* res) {
  __shared__ short As[128 * 128];
  __shared__ short Bs[128 * 128];
  const int tid = threadIdx.x;
  const int bm = blockIdx.x, bn = blockIdx.y;
  const int lane = tid & 63, wv = tid >> 6;
  const int wm = wv >> 1, wn = wv & 1;
  const int g = lane >> 4, li = lane & 15;

  f4vec acc[4][4];
  const f4vec fz = {0.f, 0.f, 0.f, 0.f};
#pragma unroll
  for (int mi = 0; mi < 4; ++mi)
#pragma unroll
    for (int ni = 0; ni < 4; ++ni) acc[mi][ni] = fz;

  const int KB = KTOT / 128;
  for (int kb = 0; kb < KB; ++kb) {
    if (kb) __syncthreads();
#pragma unroll
    for (int it = 0; it < 8; ++it) {
      int idx = it * 256 + tid;
      int row = idx >> 4, c8 = idx & 15;
      s8vec va = *(const s8vec*)(A + (size_t)(bm * 128 + row) * KTOT + kb * 128 + c8 * 8);
      *(s8vec*)(As + row * 128 + ((c8 ^ (row & 7)) << 3)) = va;
      s8vec vb = *(const s8vec*)(W + (size_t)(bn * 128 + row) * KTOT + kb * 128 + c8 * 8);
      *(s8vec*)(Bs + row * 128 + ((c8 ^ (row & 7)) << 3)) = vb;
    }
    __syncthreads();
#pragma unroll
    for (int kk = 0; kk < 4; ++kk) {
      s8vec af[4], bw[4];
#pragma unroll
      for (int mi = 0; mi < 4; ++mi) {
        int rA = wm * 64 + mi * 16 + li;
        af[mi] = *(const s8vec*)(As + rA * 128 + (((kk * 4 + g) ^ (rA & 7)) << 3));
      }
#pragma unroll
      for (int ni = 0; ni < 4; ++ni) {
        int rB = wn * 64 + ni * 16 + li;
        bw[ni] = *(const s8vec*)(Bs + rB * 128 + (((kk * 4 + g) ^ (rB & 7)) << 3));
      }
#pragma unroll
      for (int mi = 0; mi < 4; ++mi)
#pragma unroll
        for (int ni = 0; ni < 4; ++ni) acc[mi][ni] = MFMA(af[mi], bw[ni], acc[mi][ni]);
    }
  }

  // epilogue
#pragma unroll
  for (int mi = 0; mi < 4; ++mi)
#pragma unroll
    for (int ni = 0; ni < 4; ++ni)
#pragma unroll
      for (int r = 0; r < 4; ++r) {
        int row = bm * 128 + wm * 64 + mi * 16 + g * 4 + r;
        int col = bn * 128 + wn * 64 + ni * 16 + li;
        float v = acc[mi][ni][r] + bias[col];
        if constexpr (MODE == 0) {
          int head = col / 96, rem = col % 96;
          int tt = rem >> 5, hd = rem & 31;
          int wi = row >> 6, n = row & 63;
          size_t base = ((size_t)(wi * 4 + head) * 3 + tt) * 2048;
          size_t dst = base + (tt < 2 ? (size_t)(n * 32 + hd) : (size_t)(hd * 64 + n));
          outb[dst] = (short)f2bf(v);
        } else if constexpr (MODE == 1) {
          int wi = row >> 6, n = row & 63;
          int bb = wi >> 6, hy = (wi >> 3) & 7, wx = wi & 7;
          int sy = n >> 3, sx = n & 7;
          int py = (sy * 8 + hy + 8) & 63, px = (sx * 8 + wx + 8) & 63;
          size_t dst = ((size_t)(bb * 4096 + py * 64 + px)) * 128 + col;
          outf[dst] = res[dst] + v;
        } else if constexpr (MODE == 2) {
          float ge = 0.5f * v * (1.f + erff(v * 0.70710678118f));
          outb[(size_t)row * 512 + col] = (short)f2bf(ge);
        } else {  // MODE 3
          size_t dst = (size_t)row * 128 + col;
          outf[dst] = res[dst] + v;
        }
      }
}

// ---------- K3: windowed attention, 1 block = 1 window, 1 wave = 1 head ----------
__global__ __launch_bounds__(256) void attn_k(const short* __restrict__ qkv,
                                              short* __restrict__ aout) {
  __shared__ short P[4][4096];  // per-wave 64x64 bf16 (XOR-swizzled rows)
  int wi = blockIdx.x;
  int h = threadIdx.x >> 6, lane = threadIdx.x & 63;
  int g = lane >> 4, li = lane & 15;
  const short* base = qkv + ((size_t)(wi * 4 + h)) * 3 * 2048;

  s8vec qf[4], kf[4];
#pragma unroll
  for (int mi = 0; mi < 4; ++mi)
    qf[mi] = *(const s8vec*)(base + (mi * 16 + li) * 32 + g * 8);
#pragma unroll
  for (int ni = 0; ni < 4; ++ni)
    kf[ni] = *(const s8vec*)(base + 2048 + (ni * 16 + li) * 32 + g * 8);

  f4vec e[4][4];
  const f4vec fz = {0.f, 0.f, 0.f, 0.f};
#pragma unroll
  for (int mi = 0; mi < 4; ++mi)
#pragma unroll
    for (int ni = 0; ni < 4; ++ni) e[mi][ni] = fz;
#pragma unroll
  for (int mi = 0; mi < 4; ++mi)
#pragma unroll
    for (int ni = 0; ni < 4; ++ni) e[mi][ni] = MFMA(qf[mi], kf[ni], e[mi][ni]);

  const float scale = 0.17677669529663687f;  // 1/sqrt(32); "+1.0" cancels in softmax
  short* Pm = P[h];
#pragma unroll
  for (int mi = 0; mi < 4; ++mi) {
#pragma unroll
    for (int r = 0; r < 4; ++r) {
      float mx = e[mi][0][r];
#pragma unroll
      for (int ni = 1; ni < 4; ++ni) mx = fmaxf(mx, e[mi][ni][r]);
#pragma unroll
      for (int m = 1; m < 16; m <<= 1) mx = fmaxf(mx, __shfl_xor(mx, m));
      float pr[4], s = 0.f;
#pragma unroll
      for (int ni = 0; ni < 4; ++ni) {
        pr[ni] = __expf((e[mi][ni][r] - mx) * scale);
        s += pr[ni];
      }
#pragma unroll
      for (int m = 1; m < 16; m <<= 1) s += __shfl_xor(s, m);
      float inv = 1.0f / s;
      int i = mi * 16 + g * 4 + r;
#pragma unroll
      for (int ni = 0; ni < 4; ++ni) {
        int j = ni * 16 + li;
        Pm[i * 64 + ((((j >> 3) ^ (i & 7)) << 3) | (j & 7))] = (short)f2bf(pr[ni] * inv);
      }
    }
  }

  const short* vt = base + 4096;  // V^T [32][64]
  s8vec vf[2][2];
#pragma unroll
  for (int di = 0; di < 2; ++di)
#pragma unroll
    for (int kk = 0; kk < 2; ++kk)
      vf[di][kk] = *(const s8vec*)(vt + (di * 16 + li) * 64 + kk * 32 + g * 8);

  f4vec o[4][2];
#pragma unroll
  for (int mi = 0; mi < 4; ++mi)
#pragma unroll
    for (int di = 0; di < 2; ++di) o[mi][di] = fz;
#pragma unroll
  for (int kk = 0; kk < 2; ++kk) {
#pragma unroll
    for (int mi = 0; mi < 4; ++mi) {
      int rp = mi * 16 + li;
      s8vec pa = *(const s8vec*)(Pm + rp * 64 + (((kk * 4 + g) ^ (rp & 7)) << 3));
#pragma unroll
      for (int di = 0; di < 2; ++di) o[mi][di] = MFMA(pa, vf[di][kk], o[mi][di]);
    }
  }
#pragma unroll
  for (int mi = 0; mi < 4; ++mi)
#pragma unroll
    for (int di = 0; di < 2; ++di)
#pragma unroll
      for (int r = 0; r < 4; ++r) {
        int i = mi * 16 + g * 4 + r, d = di * 16 + li;
        aout[((size_t)wi * 64 + i) * 128 + h * 32 + d] = (short)f2bf(o[mi][di][r]);
      }
}

// ---------- launch ----------
extern "C" void kernel_launch(void* const* d_in, const int* in_sizes, int n_in,
                              void* d_out, int out_size, void* d_ws, size_t ws_size,
                              hipStream_t stream) {
  const float* x     = (const float*)d_in[0];
  const float* ln1w  = (const float*)d_in[1];
  const float* ln1b  = (const float*)d_in[2];
  const float* qkvw  = (const float*)d_in[3];
  const float* qkvb  = (const float*)d_in[4];
  const float* projw = (const float*)d_in[5];
  const float* projb = (const float*)d_in[6];
  const float* ln2w  = (const float*)d_in[7];
  const float* ln2b  = (const float*)d_in[8];
  const float* fc1w  = (const float*)d_in[9];
  const float* fc1b  = (const float*)d_in[10];
  const float* fc2w  = (const float*)d_in[11];
  const float* fc2b  = (const float*)d_in[12];

  char* ws = (char*)d_ws;
  short* wb   = (short*)(ws);                 // 196608 bf16 weights
  short* awin = (short*)(ws + 524288);        // 33.5 MB  (LN1 windowed, bf16)
  short* qkvB = (short*)(ws + 34078720);      // 100.7 MB (q,k,vT per win*head)
  short* hid  = (short*)(ws + 524288);        // 134.2 MB (aliases awin+qkvB)
  short* att  = (short*)(ws + 134742016);     // 33.5 MB  (attn out / ln2 out)
  short* ln2o = att;
  float* out  = (float*)d_out;

  wconv_k<<<768, 256, 0, stream>>>(qkvw, projw, fc1w, fc2w, wb);
  ln_k<1><<<32768, 256, 0, stream>>>(x, ln1w, ln1b, awin);
  gemm_k<0, 128><<<dim3(1024, 3), 256, 0, stream>>>(awin, wb, qkvb, qkvB, nullptr, nullptr);
  attn_k<<<2048, 256, 0, stream>>>(qkvB, att);
  gemm_k<1, 128><<<dim3(1024, 1), 256, 0, stream>>>(att, wb + 49152, projb, nullptr, out, x);
  ln_k<0><<<32768, 256, 0, stream>>>(out, ln2w, ln2b, ln2o);
  gemm_k<2, 128><<<dim3(1024, 4), 256, 0, stream>>>(ln2o, wb + 65536, fc1b, hid, nullptr, nullptr);
  gemm_k<3, 512><<<dim3(1024, 1), 256, 0, stream>>>(hid, wb + 131072, fc2b, nullptr, out, out);
}